// Round 4
// baseline (841.645 us; speedup 1.0000x reference)
//
#include <hip/hip_runtime.h>
#include <math.h>

#define N_NODES 100000
#define N_EDGES 1200000
#define HIDDEN  64
#define SCAN_BLOCKS ((N_NODES + 1023) / 1024)   // 98
#define GNN_BLOCKS (N_NODES / 16)               // 6250: 4 waves x 4 nodes per block
#define HEAD_BLOCKS (N_NODES / 4)               // 25000

// broadcast a float from physical lane l (uniform l) via v_readlane -> SGPR operand
__device__ __forceinline__ float bcastf(float v, int l) {
    return __uint_as_float(__builtin_amdgcn_readlane(__float_as_uint(v), (unsigned)l));
}

// ---------------------------------------------------------------- utilities

__global__ __launch_bounds__(256) void zero_u32(unsigned* __restrict__ p, int n) {
    int i = blockIdx.x * 256 + threadIdx.x;
    if (i < n) p[i] = 0u;
}

// ---------------------------------------------------------------- CSR build

__global__ __launch_bounds__(256) void hist_kernel(const int* __restrict__ dst,
                                                   unsigned* __restrict__ cnt) {
    int e = blockIdx.x * 256 + threadIdx.x;
    if (e < N_EDGES) atomicAdd(&cnt[dst[e]], 1u);
}

__global__ __launch_bounds__(256) void scan_partial(const unsigned* __restrict__ cnt,
                                                    unsigned* __restrict__ pre,
                                                    unsigned* __restrict__ bsum) {
    __shared__ unsigned lds[256];
    const int t = threadIdx.x;
    const int base = blockIdx.x * 1024 + t * 4;
    unsigned v0 = 0, v1 = 0, v2 = 0, v3 = 0;
    if (base < N_NODES) {
        const uint4 q = *(const uint4*)(cnt + base);
        v0 = q.x; v1 = q.y; v2 = q.z; v3 = q.w;
    }
    const unsigned s = v0 + v1 + v2 + v3;
    lds[t] = s;
    __syncthreads();
    for (int off = 1; off < 256; off <<= 1) {
        unsigned u = (t >= off) ? lds[t - off] : 0u;
        __syncthreads();
        lds[t] += u;
        __syncthreads();
    }
    const unsigned excl = lds[t] - s;
    if (base < N_NODES) {
        uint4 o;
        o.x = excl;
        o.y = excl + v0;
        o.z = excl + v0 + v1;
        o.w = excl + v0 + v1 + v2;
        *(uint4*)(pre + base) = o;
    }
    if (t == 255) bsum[blockIdx.x] = lds[255];
}

__global__ __launch_bounds__(128) void scan_bsum(unsigned* __restrict__ bsum) {
    __shared__ unsigned lds[128];
    const int t = threadIdx.x;
    unsigned s = (t < SCAN_BLOCKS) ? bsum[t] : 0u;
    lds[t] = s;
    __syncthreads();
    for (int off = 1; off < 128; off <<= 1) {
        unsigned u = (t >= off) ? lds[t - off] : 0u;
        __syncthreads();
        lds[t] += u;
        __syncthreads();
    }
    if (t < SCAN_BLOCKS) bsum[t] = lds[t] - s;
}

__global__ __launch_bounds__(256) void scan_final(const unsigned* __restrict__ cnt,
                                                  const unsigned* __restrict__ pre,
                                                  const unsigned* __restrict__ bsum,
                                                  unsigned* __restrict__ rowptr,
                                                  float* __restrict__ invcnt) {
    const int t = threadIdx.x;
    const int base = blockIdx.x * 1024 + t * 4;
    if (base < N_NODES) {
        const unsigned off = bsum[blockIdx.x];
        uint4 p = *(const uint4*)(pre + base);
        const uint4 cq = *(const uint4*)(cnt + base);
        p.x += off; p.y += off; p.z += off; p.w += off;
        *(uint4*)(rowptr + base) = p;
        float4 ic;
        ic.x = 1.0f / (float)(cq.x + 1u);
        ic.y = 1.0f / (float)(cq.y + 1u);
        ic.z = 1.0f / (float)(cq.z + 1u);
        ic.w = 1.0f / (float)(cq.w + 1u);
        *(float4*)(invcnt + base) = ic;
    }
    if (blockIdx.x == 0 && t == 0) rowptr[N_NODES] = N_EDGES;
}

__global__ __launch_bounds__(256) void fill_csr(const int* __restrict__ src,
                                                const int* __restrict__ dst,
                                                const unsigned* __restrict__ rowptr,
                                                unsigned* __restrict__ fillc,
                                                unsigned* __restrict__ csr) {
    int e = blockIdx.x * 256 + threadIdx.x;
    if (e < N_EDGES) {
        int d = dst[e];
        unsigned pos = rowptr[d] + atomicAdd(&fillc[d], 1u);
        csr[pos] = (unsigned)src[e];
    }
}

// ---------------------------------------------------------------- per-layer

// y[n,:] = hprev[n,:] @ W  (bias folded post-mean). 16 nodes/block, 4/wave.
// W staged in LDS as row-pair-interleaved float2 so the GEMM reads ds_read_b64.
template <int IN1>
__global__ __launch_bounds__(256) void linear_y(const float* __restrict__ hprev,
                                                const float* __restrict__ W,
                                                float* __restrict__ y) {
    constexpr int HP_PAIRS = IN1 / 2;
    constexpr int HP_REM = IN1 & 1;
    __shared__ float Wl[HP_PAIRS * 128 + (HP_REM ? 64 : 0)];
    const int tid = threadIdx.x;
    for (int j = tid; j < IN1 * 64; j += 256) {
        const int i = j >> 6, cc = j & 63;
        const float v = W[j];
        if (i < 2 * HP_PAIRS) Wl[(((i >> 1) * 64 + cc) << 1) | (i & 1)] = v;
        else                  Wl[HP_PAIRS * 128 + cc] = v;
    }
    __syncthreads();
    const int w = tid >> 6, lane = tid & 63;
    const float2* WlP = (const float2*)Wl;
    for (int rep = 0; rep < 4; ++rep) {
        const int n = blockIdx.x * 16 + w * 4 + rep;
        const float hpv = hprev[n * IN1 + (lane < IN1 ? lane : 0)];
        float acc = 0.f;
#pragma unroll
        for (int k = 0; k < HP_PAIRS; ++k) {
            const float2 u = WlP[k * 64 + lane];
            acc += bcastf(hpv, 2 * k) * u.x + bcastf(hpv, 2 * k + 1) * u.y;
        }
        if (HP_REM)
            acc += bcastf(hpv, IN1 - 1) * Wl[HP_PAIRS * 128 + lane];
        y[n * 64 + lane] = acc;
    }
}

// agg[n,:] = (y[n,:] + sum_in-edges y[src,:]) * invcnt[n] + b
// hnext[n,:] = relu([hprev, agg] @ U + c)
// Gather: 16 lanes x float4 = one y row; 4 edge-groups/wave; 16 edges in flight.
// GEMM: U in LDS pair-interleaved (agg rows first), v broadcast via v_readlane.
template <int IN1>
__global__ __launch_bounds__(256) void fused_agg_update(const float* __restrict__ hprev,
                                                        const float* __restrict__ y,
                                                        const unsigned* __restrict__ csr,
                                                        const unsigned* __restrict__ rowptr,
                                                        const float* __restrict__ invcnt,
                                                        const float* __restrict__ b,
                                                        const float* __restrict__ U,
                                                        const float* __restrict__ c,
                                                        float* __restrict__ hnext) {
    constexpr int HP_PAIRS = IN1 / 2;
    constexpr int HP_REM = IN1 & 1;
    __shared__ float Ua[32 * 128];                          // 64 agg rows as 32 pairs (16 KiB)
    __shared__ float Uh[HP_PAIRS * 128 + (HP_REM ? 64 : 0)];
    const int tid = threadIdx.x;
    for (int j = tid; j < (IN1 + 64) * 64; j += 256) {
        const int i = j >> 6, cc = j & 63;
        const float v = U[j];
        if (i < IN1) {
            if (i < 2 * HP_PAIRS) Uh[(((i >> 1) * 64 + cc) << 1) | (i & 1)] = v;
            else                  Uh[HP_PAIRS * 128 + cc] = v;
        } else {
            const int a = i - IN1;
            Ua[(((a >> 1) * 64 + cc) << 1) | (a & 1)] = v;
        }
    }
    __syncthreads();
    const int w = tid >> 6, lane = tid & 63, g = lane >> 4, q = lane & 15;
    const float4* Y4 = (const float4*)y;
    const float4 b4 = ((const float4*)b)[q];
    const float2* UaP = (const float2*)Ua;
    const float2* UhP = (const float2*)Uh;
    const float cl = c[lane];

    for (int rep = 0; rep < 4; ++rep) {
        const int n = blockIdx.x * 16 + w * 4 + rep;
        float4 acc;
        if (g == 0) acc = Y4[n * 16 + q];                   // self loop
        else { acc.x = 0.f; acc.y = 0.f; acc.z = 0.f; acc.w = 0.f; }
        const unsigned e1 = rowptr[n + 1];
        unsigned e = rowptr[n];
        for (; e + 16 <= e1; e += 16) {                     // 16 edges in flight
            const unsigned i0 = csr[e + g];
            const unsigned i1 = csr[e + 4 + g];
            const unsigned i2 = csr[e + 8 + g];
            const unsigned i3 = csr[e + 12 + g];
            const float4 a0 = Y4[i0 * 16 + q];
            const float4 a1 = Y4[i1 * 16 + q];
            const float4 a2 = Y4[i2 * 16 + q];
            const float4 a3 = Y4[i3 * 16 + q];
            acc.x += (a0.x + a1.x) + (a2.x + a3.x);
            acc.y += (a0.y + a1.y) + (a2.y + a3.y);
            acc.z += (a0.z + a1.z) + (a2.z + a3.z);
            acc.w += (a0.w + a1.w) + (a2.w + a3.w);
        }
        for (; e < e1; e += 4) {                            // remainder, 4 edges/pass
            if (e + g < e1) {
                const unsigned i = csr[e + g];
                const float4 a = Y4[i * 16 + q];
                acc.x += a.x; acc.y += a.y; acc.z += a.z; acc.w += a.w;
            }
        }
        // fold the 4 edge-groups
        acc.x += __shfl_xor(acc.x, 16); acc.x += __shfl_xor(acc.x, 32);
        acc.y += __shfl_xor(acc.y, 16); acc.y += __shfl_xor(acc.y, 32);
        acc.z += __shfl_xor(acc.z, 16); acc.z += __shfl_xor(acc.z, 32);
        acc.w += __shfl_xor(acc.w, 16); acc.w += __shfl_xor(acc.w, 32);
        const float iv = invcnt[n];
        acc.x = acc.x * iv + b4.x;
        acc.y = acc.y * iv + b4.y;
        acc.z = acc.z * iv + b4.z;
        acc.w = acc.w * iv + b4.w;

        const float hpv = hprev[n * IN1 + (lane < IN1 ? lane : 0)];
        float out = cl;
#pragma unroll
        for (int k = 0; k < 32; ++k) {                      // agg rows 2k,2k+1
            const float2 u = UaP[k * 64 + lane];
            float v0, v1;
            if ((k & 1) == 0) { v0 = bcastf(acc.x, k >> 1); v1 = bcastf(acc.y, k >> 1); }
            else              { v0 = bcastf(acc.z, k >> 1); v1 = bcastf(acc.w, k >> 1); }
            out += v0 * u.x + v1 * u.y;
        }
#pragma unroll
        for (int k = 0; k < HP_PAIRS; ++k) {                // hprev rows 2k,2k+1
            const float2 u = UhP[k * 64 + lane];
            out += bcastf(hpv, 2 * k) * u.x + bcastf(hpv, 2 * k + 1) * u.y;
        }
        if (HP_REM)
            out += bcastf(hpv, IN1 - 1) * Uh[HP_PAIRS * 128 + lane];
        hnext[n * 64 + lane] = fmaxf(out, 0.f);
    }
}

// ---------------------------------------------------------------- heads

__global__ __launch_bounds__(256) void heads_kernel(const float* __restrict__ h,
                                                    const float* __restrict__ Ws,
                                                    const float* __restrict__ bs,
                                                    const float* __restrict__ Wst,
                                                    const float* __restrict__ bst,
                                                    const float* __restrict__ Wo,
                                                    const float* __restrict__ bo,
                                                    float* __restrict__ state,
                                                    float* __restrict__ part) {
    const int tid = threadIdx.x, w = tid >> 6, lane = tid & 63;
    const int n = blockIdx.x * 4 + w;
    float hv = h[n * 64 + lane];
    float s0 = hv * Ws[lane * 2 + 0];
    float s1 = hv * Ws[lane * 2 + 1];
    float st = hv * Wst[lane];
    float oc = hv * Wo[lane];
#pragma unroll
    for (int off = 32; off; off >>= 1) {
        s0 += __shfl_down(s0, off);
        s1 += __shfl_down(s1, off);
        st += __shfl_down(st, off);
        oc += __shfl_down(oc, off);
    }
    __shared__ float red[4][2];
    if (lane == 0) {
        state[n * 2 + 0] = s0 + bs[0];
        state[n * 2 + 1] = s1 + bs[1];
        red[w][0] = 1.0f / (1.0f + __expf(-(st + bst[0])));
        red[w][1] = oc + bo[0];
    }
    __syncthreads();
    if (tid == 0) {
        part[blockIdx.x * 2 + 0] = red[0][0] + red[1][0] + red[2][0] + red[3][0];
        part[blockIdx.x * 2 + 1] = red[0][1] + red[1][1] + red[2][1] + red[3][1];
    }
}

__global__ __launch_bounds__(1024) void final_reduce(const float* __restrict__ part,
                                                     float* __restrict__ scal) {
    __shared__ float l0[1024], l1[1024];
    const int t = threadIdx.x;
    float a = 0.f, b = 0.f;
    for (int i = t; i < HEAD_BLOCKS; i += 1024) { a += part[2 * i]; b += part[2 * i + 1]; }
    l0[t] = a; l1[t] = b;
    __syncthreads();
    for (int off = 512; off; off >>= 1) {
        if (t < off) { l0[t] += l0[t + off]; l1[t] += l1[t + off]; }
        __syncthreads();
    }
    if (t == 0) {
        scal[0] = l0[0] / (float)N_NODES;   // stability
        scal[1] = l1[0] / (float)N_NODES;   // opf_cost
    }
}

// ---------------------------------------------------------------- launch

extern "C" void kernel_launch(void* const* d_in, const int* in_sizes, int n_in,
                              void* d_out, int out_size, void* d_ws, size_t ws_size,
                              hipStream_t stream) {
    const float* x   = (const float*)d_in[0];
    const int*   ei  = (const int*)d_in[1];
    const float* W1  = (const float*)d_in[2];
    const float* b1  = (const float*)d_in[3];
    const float* U1  = (const float*)d_in[4];
    const float* c1  = (const float*)d_in[5];
    const float* W2  = (const float*)d_in[6];
    const float* b2  = (const float*)d_in[7];
    const float* U2  = (const float*)d_in[8];
    const float* c2  = (const float*)d_in[9];
    const float* W3  = (const float*)d_in[10];
    const float* b3  = (const float*)d_in[11];
    const float* U3  = (const float*)d_in[12];
    const float* c3  = (const float*)d_in[13];
    const float* Ws  = (const float*)d_in[14];
    const float* bs  = (const float*)d_in[15];
    const float* Wst = (const float*)d_in[16];
    const float* bst = (const float*)d_in[17];
    const float* Wo  = (const float*)d_in[18];
    const float* bo  = (const float*)d_in[19];

    const int* src = ei;              // edge_index[0]
    const int* dst = ei + N_EDGES;    // edge_index[1]

    char* wsp = (char*)d_ws;
    size_t off = 0;
    auto alloc = [&](size_t bytes) -> char* {
        char* p = wsp + off;
        off = (off + bytes + 255) & ~(size_t)255;
        return p;
    };
    unsigned* cnt    = (unsigned*)alloc((size_t)N_NODES * 4);
    unsigned* fillc  = (unsigned*)alloc((size_t)N_NODES * 4);
    unsigned* rowptr = (unsigned*)alloc((size_t)(N_NODES + 1) * 4);
    float*    invcnt = (float*)   alloc((size_t)N_NODES * 4);
    unsigned* pre    = (unsigned*)alloc((size_t)N_NODES * 4);
    unsigned* bsum   = (unsigned*)alloc((size_t)SCAN_BLOCKS * 4);
    unsigned* csr    = (unsigned*)alloc((size_t)N_EDGES * 4);
    float*    part   = (float*)   alloc((size_t)HEAD_BLOCKS * 2 * 4);
    float*    ybuf   = (float*)   alloc((size_t)N_NODES * HIDDEN * 4);
    float*    hA     = (float*)   alloc((size_t)N_NODES * HIDDEN * 4);
    float*    hB     = (float*)   alloc((size_t)N_NODES * HIDDEN * 4);

    float* out   = (float*)d_out;
    float* state = out;                 // [N, 2]
    float* scal  = out + 200000;        // stability, opf_cost
    float* hout  = out + 200002;        // [N, 64] (8B-aligned only: scalar access!)

    const int EB = (N_EDGES + 255) / 256;   // 4688
    const int NB = (N_NODES + 255) / 256;   // 391

    // CSR build (exact-extent zeroing — see R1 poison bug)
    zero_u32<<<NB, 256, 0, stream>>>(cnt,   N_NODES);
    zero_u32<<<NB, 256, 0, stream>>>(fillc, N_NODES);
    hist_kernel<<<EB, 256, 0, stream>>>(dst, cnt);
    scan_partial<<<SCAN_BLOCKS, 256, 0, stream>>>(cnt, pre, bsum);
    scan_bsum<<<1, 128, 0, stream>>>(bsum);
    scan_final<<<SCAN_BLOCKS, 256, 0, stream>>>(cnt, pre, bsum, rowptr, invcnt);
    fill_csr<<<EB, 256, 0, stream>>>(src, dst, rowptr, fillc, csr);

    // layer 1 (in = 5)
    linear_y<5><<<GNN_BLOCKS, 256, 0, stream>>>(x, W1, ybuf);
    fused_agg_update<5><<<GNN_BLOCKS, 256, 0, stream>>>(x, ybuf, csr, rowptr, invcnt,
                                                        b1, U1, c1, hA);
    // layer 2 (in = 64)
    linear_y<64><<<GNN_BLOCKS, 256, 0, stream>>>(hA, W2, ybuf);
    fused_agg_update<64><<<GNN_BLOCKS, 256, 0, stream>>>(hA, ybuf, csr, rowptr, invcnt,
                                                         b2, U2, c2, hB);
    // layer 3 (in = 64) — h written straight into d_out
    linear_y<64><<<GNN_BLOCKS, 256, 0, stream>>>(hB, W3, ybuf);
    fused_agg_update<64><<<GNN_BLOCKS, 256, 0, stream>>>(hB, ybuf, csr, rowptr, invcnt,
                                                         b3, U3, c3, hout);
    // heads
    heads_kernel<<<HEAD_BLOCKS, 256, 0, stream>>>(hout, Ws, bs, Wst, bst, Wo, bo, state, part);
    final_reduce<<<1, 1024, 0, stream>>>(part, scal);
}

// Round 5
// 543.839 us; speedup vs baseline: 1.5476x; 1.5476x over previous
//
#include <hip/hip_runtime.h>
#include <math.h>

#define N_NODES 100000
#define N_EDGES 1200000
#define HIDDEN  64
#define SCAN_BLOCKS ((N_NODES + 1023) / 1024)   // 98
#define MP_BLOCKS (N_NODES / 8)                 // 12500: 8 waves x 1 node/wave
#define HEAD_BLOCKS (N_NODES / 4)               // 25000

// broadcast a float from lane l (uniform l) via v_readlane
__device__ __forceinline__ float bcastf(float v, int l) {
    return __uint_as_float(__builtin_amdgcn_readlane(__float_as_uint(v), (unsigned)l));
}

// ---------------------------------------------------------------- utilities

__global__ __launch_bounds__(256) void zero_u32(unsigned* __restrict__ p, int n) {
    int i = blockIdx.x * 256 + threadIdx.x;
    if (i < n) p[i] = 0u;
}

// ---------------------------------------------------------------- CSR build

__global__ __launch_bounds__(256) void hist_kernel(const int* __restrict__ dst,
                                                   unsigned* __restrict__ cnt) {
    int e = blockIdx.x * 256 + threadIdx.x;
    if (e < N_EDGES) atomicAdd(&cnt[dst[e]], 1u);
}

__global__ __launch_bounds__(256) void scan_partial(const unsigned* __restrict__ cnt,
                                                    unsigned* __restrict__ pre,
                                                    unsigned* __restrict__ bsum) {
    __shared__ unsigned lds[256];
    const int t = threadIdx.x;
    const int base = blockIdx.x * 1024 + t * 4;
    unsigned v0 = 0, v1 = 0, v2 = 0, v3 = 0;
    if (base < N_NODES) {
        const uint4 q = *(const uint4*)(cnt + base);
        v0 = q.x; v1 = q.y; v2 = q.z; v3 = q.w;
    }
    const unsigned s = v0 + v1 + v2 + v3;
    lds[t] = s;
    __syncthreads();
    for (int off = 1; off < 256; off <<= 1) {
        unsigned u = (t >= off) ? lds[t - off] : 0u;
        __syncthreads();
        lds[t] += u;
        __syncthreads();
    }
    const unsigned excl = lds[t] - s;
    if (base < N_NODES) {
        uint4 o;
        o.x = excl;
        o.y = excl + v0;
        o.z = excl + v0 + v1;
        o.w = excl + v0 + v1 + v2;
        *(uint4*)(pre + base) = o;
    }
    if (t == 255) bsum[blockIdx.x] = lds[255];
}

__global__ __launch_bounds__(128) void scan_bsum(unsigned* __restrict__ bsum) {
    __shared__ unsigned lds[128];
    const int t = threadIdx.x;
    unsigned s = (t < SCAN_BLOCKS) ? bsum[t] : 0u;
    lds[t] = s;
    __syncthreads();
    for (int off = 1; off < 128; off <<= 1) {
        unsigned u = (t >= off) ? lds[t - off] : 0u;
        __syncthreads();
        lds[t] += u;
        __syncthreads();
    }
    if (t < SCAN_BLOCKS) bsum[t] = lds[t] - s;
}

__global__ __launch_bounds__(256) void scan_final(const unsigned* __restrict__ cnt,
                                                  const unsigned* __restrict__ pre,
                                                  const unsigned* __restrict__ bsum,
                                                  unsigned* __restrict__ rowptr,
                                                  float* __restrict__ invcnt) {
    const int t = threadIdx.x;
    const int base = blockIdx.x * 1024 + t * 4;
    if (base < N_NODES) {
        const unsigned off = bsum[blockIdx.x];
        uint4 p = *(const uint4*)(pre + base);
        const uint4 cq = *(const uint4*)(cnt + base);
        p.x += off; p.y += off; p.z += off; p.w += off;
        *(uint4*)(rowptr + base) = p;
        float4 ic;
        ic.x = 1.0f / (float)(cq.x + 1u);
        ic.y = 1.0f / (float)(cq.y + 1u);
        ic.z = 1.0f / (float)(cq.z + 1u);
        ic.w = 1.0f / (float)(cq.w + 1u);
        *(float4*)(invcnt + base) = ic;
    }
    if (blockIdx.x == 0 && t == 0) rowptr[N_NODES] = N_EDGES;
}

__global__ __launch_bounds__(256) void fill_csr(const int* __restrict__ src,
                                                const int* __restrict__ dst,
                                                const unsigned* __restrict__ rowptr,
                                                unsigned* __restrict__ fillc,
                                                unsigned* __restrict__ csr) {
    int e = blockIdx.x * 256 + threadIdx.x;
    if (e < N_EDGES) {
        int d = dst[e];
        unsigned pos = rowptr[d] + atomicAdd(&fillc[d], 1u);
        csr[pos] = (unsigned)src[e];
    }
}

// ---------------------------------------------------------------- per-layer weight folding
// V2 = W @ U_bot  [IN,64];  cp = c + b @ U_bot  [64]
// (h = relu(hprev@U_top + m@V2 + cp), m = mean of hprev rows incl. self)
template <int IN>
__global__ __launch_bounds__(256) void precompute_v(const float* __restrict__ W,
                                                    const float* __restrict__ b,
                                                    const float* __restrict__ U,
                                                    const float* __restrict__ c,
                                                    float* __restrict__ V2,
                                                    float* __restrict__ cp) {
    __shared__ float Ub[64 * 64];     // U_bot, 16 KiB
    const int tid = threadIdx.x;
    for (int j = tid; j < 64 * 64; j += 256) Ub[j] = U[IN * 64 + j];
    __syncthreads();
    const int w = tid >> 6, lane = tid & 63;
    const int r = blockIdx.x * 4 + w;
    if (r > IN) return;
    const float wv = (r < IN) ? W[r * 64 + lane] : b[lane];
    float o = (r < IN) ? 0.f : c[lane];
#pragma unroll 8
    for (int k = 0; k < 64; ++k) o += bcastf(wv, k) * Ub[k * 64 + lane];
    if (r < IN) V2[r * 64 + lane] = o;
    else        cp[lane] = o;
}

// ---------------------------------------------------------------- the layer kernel
// One node per wave. Gather-mean hprev rows (coalesced lane loads), then
// out[lane] = cp[lane] + sum_k hp[k]*U_top[k][lane] + m[k]*V2[k][lane], relu.
// U_top & V2 staged interleaved as float2 in LDS (one ds_read_b64 per k).
template <int IN>
__global__ __launch_bounds__(512, 4) void mp_layer(const float* __restrict__ hprev,
                                                   const unsigned* __restrict__ csr,
                                                   const unsigned* __restrict__ rowptr,
                                                   const float* __restrict__ invcnt,
                                                   const float* __restrict__ Utop,
                                                   const float* __restrict__ V2,
                                                   const float* __restrict__ cp,
                                                   float* __restrict__ hnext) {
    __shared__ float2 T[IN * 64];     // (U_top[k][lane], V2[k][lane])  <=32 KiB
    const int tid = threadIdx.x;
    for (int j = tid; j < IN * 64; j += 512) T[j] = make_float2(Utop[j], V2[j]);
    __syncthreads();
    const int w = tid >> 6, lane = tid & 63;
    const int n = blockIdx.x * 8 + w;

    const float hp = (lane < IN) ? hprev[n * IN + lane] : 0.f;
    float m = hp;                                      // self loop
    const unsigned e1 = rowptr[n + 1];
    unsigned e = rowptr[n];
    for (; e + 4 <= e1; e += 4) {                      // 4 edges in flight per wave
        const unsigned s0 = csr[e], s1 = csr[e + 1], s2 = csr[e + 2], s3 = csr[e + 3];
        const float a0 = (lane < IN) ? hprev[s0 * IN + lane] : 0.f;
        const float a1 = (lane < IN) ? hprev[s1 * IN + lane] : 0.f;
        const float a2 = (lane < IN) ? hprev[s2 * IN + lane] : 0.f;
        const float a3 = (lane < IN) ? hprev[s3 * IN + lane] : 0.f;
        m += (a0 + a1) + (a2 + a3);
    }
    for (; e < e1; ++e)
        m += (lane < IN) ? hprev[csr[e] * IN + lane] : 0.f;
    m *= invcnt[n];

    float out = cp[lane];
#pragma unroll 8
    for (int k = 0; k < IN; ++k) {
        const float2 u = T[k * 64 + lane];
        out += bcastf(hp, k) * u.x + bcastf(m, k) * u.y;
    }
    hnext[n * 64 + lane] = fmaxf(out, 0.f);
}

// ---------------------------------------------------------------- heads

__global__ __launch_bounds__(256) void heads_kernel(const float* __restrict__ h,
                                                    const float* __restrict__ Ws,
                                                    const float* __restrict__ bs,
                                                    const float* __restrict__ Wst,
                                                    const float* __restrict__ bst,
                                                    const float* __restrict__ Wo,
                                                    const float* __restrict__ bo,
                                                    float* __restrict__ state,
                                                    float* __restrict__ part) {
    const int tid = threadIdx.x, w = tid >> 6, lane = tid & 63;
    const int n = blockIdx.x * 4 + w;
    float hv = h[n * 64 + lane];
    float s0 = hv * Ws[lane * 2 + 0];
    float s1 = hv * Ws[lane * 2 + 1];
    float st = hv * Wst[lane];
    float oc = hv * Wo[lane];
#pragma unroll
    for (int off = 32; off; off >>= 1) {
        s0 += __shfl_down(s0, off);
        s1 += __shfl_down(s1, off);
        st += __shfl_down(st, off);
        oc += __shfl_down(oc, off);
    }
    __shared__ float red[4][2];
    if (lane == 0) {
        state[n * 2 + 0] = s0 + bs[0];
        state[n * 2 + 1] = s1 + bs[1];
        red[w][0] = 1.0f / (1.0f + __expf(-(st + bst[0])));
        red[w][1] = oc + bo[0];
    }
    __syncthreads();
    if (tid == 0) {
        part[blockIdx.x * 2 + 0] = red[0][0] + red[1][0] + red[2][0] + red[3][0];
        part[blockIdx.x * 2 + 1] = red[0][1] + red[1][1] + red[2][1] + red[3][1];
    }
}

__global__ __launch_bounds__(1024) void final_reduce(const float* __restrict__ part,
                                                     float* __restrict__ scal) {
    __shared__ float l0[1024], l1[1024];
    const int t = threadIdx.x;
    float a = 0.f, b = 0.f;
    for (int i = t; i < HEAD_BLOCKS; i += 1024) { a += part[2 * i]; b += part[2 * i + 1]; }
    l0[t] = a; l1[t] = b;
    __syncthreads();
    for (int off = 512; off; off >>= 1) {
        if (t < off) { l0[t] += l0[t + off]; l1[t] += l1[t + off]; }
        __syncthreads();
    }
    if (t == 0) {
        scal[0] = l0[0] / (float)N_NODES;   // stability
        scal[1] = l1[0] / (float)N_NODES;   // opf_cost
    }
}

// ---------------------------------------------------------------- launch

extern "C" void kernel_launch(void* const* d_in, const int* in_sizes, int n_in,
                              void* d_out, int out_size, void* d_ws, size_t ws_size,
                              hipStream_t stream) {
    const float* x   = (const float*)d_in[0];
    const int*   ei  = (const int*)d_in[1];
    const float* W1  = (const float*)d_in[2];
    const float* b1  = (const float*)d_in[3];
    const float* U1  = (const float*)d_in[4];
    const float* c1  = (const float*)d_in[5];
    const float* W2  = (const float*)d_in[6];
    const float* b2  = (const float*)d_in[7];
    const float* U2  = (const float*)d_in[8];
    const float* c2  = (const float*)d_in[9];
    const float* W3  = (const float*)d_in[10];
    const float* b3  = (const float*)d_in[11];
    const float* U3  = (const float*)d_in[12];
    const float* c3  = (const float*)d_in[13];
    const float* Ws  = (const float*)d_in[14];
    const float* bs  = (const float*)d_in[15];
    const float* Wst = (const float*)d_in[16];
    const float* bst = (const float*)d_in[17];
    const float* Wo  = (const float*)d_in[18];
    const float* bo  = (const float*)d_in[19];

    const int* src = ei;              // edge_index[0]
    const int* dst = ei + N_EDGES;    // edge_index[1]

    char* wsp = (char*)d_ws;
    size_t off = 0;
    auto alloc = [&](size_t bytes) -> char* {
        char* p = wsp + off;
        off = (off + bytes + 255) & ~(size_t)255;
        return p;
    };
    unsigned* cnt    = (unsigned*)alloc((size_t)N_NODES * 4);
    unsigned* fillc  = (unsigned*)alloc((size_t)N_NODES * 4);
    unsigned* rowptr = (unsigned*)alloc((size_t)(N_NODES + 1) * 4);
    float*    invcnt = (float*)   alloc((size_t)N_NODES * 4);
    unsigned* pre    = (unsigned*)alloc((size_t)N_NODES * 4);
    unsigned* bsum   = (unsigned*)alloc((size_t)SCAN_BLOCKS * 4);
    unsigned* csr    = (unsigned*)alloc((size_t)N_EDGES * 4);
    float*    part   = (float*)   alloc((size_t)HEAD_BLOCKS * 2 * 4);
    float*    V2a    = (float*)   alloc((size_t)5 * 64 * 4);
    float*    V2b    = (float*)   alloc((size_t)64 * 64 * 4);
    float*    V2c    = (float*)   alloc((size_t)64 * 64 * 4);
    float*    cpa    = (float*)   alloc((size_t)64 * 4);
    float*    cpb    = (float*)   alloc((size_t)64 * 4);
    float*    cpc    = (float*)   alloc((size_t)64 * 4);
    float*    hA     = (float*)   alloc((size_t)N_NODES * HIDDEN * 4);
    float*    hB     = (float*)   alloc((size_t)N_NODES * HIDDEN * 4);

    float* out   = (float*)d_out;
    float* state = out;                 // [N, 2]
    float* scal  = out + 200000;        // stability, opf_cost
    float* hout  = out + 200002;        // [N, 64]

    const int EB = (N_EDGES + 255) / 256;   // 4688
    const int NB = (N_NODES + 255) / 256;   // 391

    // weight folding (independent of graph — front-load)
    precompute_v<5> <<<2, 256, 0, stream>>>(W1, b1, U1, c1, V2a, cpa);
    precompute_v<64><<<17, 256, 0, stream>>>(W2, b2, U2, c2, V2b, cpb);
    precompute_v<64><<<17, 256, 0, stream>>>(W3, b3, U3, c3, V2c, cpc);

    // CSR build (exact-extent zeroing — see R1 poison bug)
    zero_u32<<<NB, 256, 0, stream>>>(cnt,   N_NODES);
    zero_u32<<<NB, 256, 0, stream>>>(fillc, N_NODES);
    hist_kernel<<<EB, 256, 0, stream>>>(dst, cnt);
    scan_partial<<<SCAN_BLOCKS, 256, 0, stream>>>(cnt, pre, bsum);
    scan_bsum<<<1, 128, 0, stream>>>(bsum);
    scan_final<<<SCAN_BLOCKS, 256, 0, stream>>>(cnt, pre, bsum, rowptr, invcnt);
    fill_csr<<<EB, 256, 0, stream>>>(src, dst, rowptr, fillc, csr);

    // layers: h = relu(hprev@U_top + mean@V2 + cp)
    mp_layer<5> <<<MP_BLOCKS, 512, 0, stream>>>(x,  csr, rowptr, invcnt, U1, V2a, cpa, hA);
    mp_layer<64><<<MP_BLOCKS, 512, 0, stream>>>(hA, csr, rowptr, invcnt, U2, V2b, cpb, hB);
    mp_layer<64><<<MP_BLOCKS, 512, 0, stream>>>(hB, csr, rowptr, invcnt, U3, V2c, cpc, hout);

    // heads
    heads_kernel<<<HEAD_BLOCKS, 256, 0, stream>>>(hout, Ws, bs, Wst, bst, Wo, bo, state, part);
    final_reduce<<<1, 1024, 0, stream>>>(part, scal);
}